// Round 18
// baseline (233.360 us; speedup 1.0000x reference)
//
#include <hip/hip_runtime.h>
#include <cstdint>
#include <cstddef>

#define NN   10000
#define NE   160000
#define NB   16
#define FIN  32
#define HC   16
#define NH   4
#define HD   4
#define OBSD 100
#define NOUT 30
#define HIDD 128
#define PO   15
#define BCAP 64
#define NBUCKET 64
#define EGB  640           // edge blocks (amortizes block-dispatch stream)
#define NWAVES (EGB * 4)   // 2560 edge waves, ~4 nodes each
#define HSM  8884          // MODE2 smem floats

typedef float floatx2 __attribute__((ext_vector_type(2)));

__device__ inline uint32_t pack_fp8x4(float a, float b, float c, float d) {
    int p = __builtin_amdgcn_cvt_pk_fp8_f32(a, b, 0, false);
    p = __builtin_amdgcn_cvt_pk_fp8_f32(c, d, p, true);
    return (uint32_t)p;
}

__device__ inline float4 shfl_xor4(float4 v, int m) {
    float4 r;
    r.x = __shfl_xor(v.x, m, 64);
    r.y = __shfl_xor(v.y, m, 64);
    r.z = __shfl_xor(v.z, m, 64);
    r.w = __shfl_xor(v.w, m, 64);
    return r;
}

// ---------------- bucket-CSR build + layer-0 transform (fat kernel) --------
__global__ void k_build_xform0(const int* __restrict__ src, const int* __restrict__ dst,
                               int* __restrict__ cnt, int* __restrict__ bucket,
                               const float* __restrict__ x,
                               const float* __restrict__ Wlg, const float* __restrict__ Wrg,
                               const float* __restrict__ blg, const float* __restrict__ brg,
                               uint32_t* __restrict__ xl, uint32_t* __restrict__ xr) {
    int bid = blockIdx.x;
    if (bid < 625) {
        int e = bid * 256 + threadIdx.x;
        if (e < NE) {
            int d = dst[e];
            int p = atomicAdd(&cnt[d], 1);
            if (p < BCAP) bucket[(size_t)d * BCAP + p] = src[e];
        }
        return;
    }
    __shared__ float sWl[FIN * HC], sWr[FIN * HC], sbl[HC], sbr[HC];
    for (int i = threadIdx.x; i < FIN * HC; i += 256) { sWl[i] = Wlg[i]; sWr[i] = Wrg[i]; }
    if (threadIdx.x < HC) { sbl[threadIdx.x] = blg[threadIdx.x]; sbr[threadIdx.x] = brg[threadIdx.x]; }
    __syncthreads();
    int local = bid - 625;
    int b = local / 40;
    int n = (local % 40) * 256 + threadIdx.x;
    if (n >= NN) return;
    const float4* xp4 = (const float4*)(x + ((size_t)b * NN + n) * FIN);
    float4 rowv[8];
#pragma unroll
    for (int f4 = 0; f4 < 8; f4++) rowv[f4] = xp4[f4];
    const float* row = (const float*)rowv;
    float al[HC], ar[HC];
#pragma unroll
    for (int c = 0; c < HC; c++) { al[c] = sbl[c]; ar[c] = sbr[c]; }
#pragma unroll
    for (int f = 0; f < FIN; f++) {
        float v = row[f];
#pragma unroll
        for (int c = 0; c < HC; c++) {
            al[c] = fmaf(v, sWl[f * HC + c], al[c]);
            ar[c] = fmaf(v, sWr[f * HC + c], ar[c]);
        }
    }
    uint32_t* xlo = xl + ((size_t)n * NB + b) * 4;
    uint32_t* xro = xr + ((size_t)n * NB + b) * 4;
#pragma unroll
    for (int hh = 0; hh < 4; hh++) {
        xlo[hh] = pack_fp8x4(al[hh * 4 + 0], al[hh * 4 + 1], al[hh * 4 + 2], al[hh * 4 + 3]);
        xro[hh] = pack_fp8x4(ar[hh * 4 + 0], ar[hh * 4 + 1], ar[hh * 4 + 2], ar[hh * 4 + 3]);
    }
}

// ---------------- fused edge softmax + aggregate (grid-stride nodes) --------
// one wave handles ~4 nodes; lane = b*4 + h; one uint = 4 fp8 = one head.
// MODE 1: fused next-layer 16x16 l/r transforms -> xl'(fp8)/xr'(fp8).
// MODE 2: per-wave pool accumulation -> 64-bucket atomics + relaxed tickets;
//         16 extra HEAD blocks (bid>=EGB) pre-stage weights, spin, run MLP.
template <int MODE>
__global__ __launch_bounds__(256, 4)
void k_edge_f(const uint32_t* __restrict__ xl, const uint32_t* __restrict__ xr,
              const int* __restrict__ cntg, const int* __restrict__ bucket,
              const float* __restrict__ attg, const float* __restrict__ biasg,
              const float* __restrict__ Wln, const float* __restrict__ Wrn,
              const float* __restrict__ bln, const float* __restrict__ brn,
              uint32_t* __restrict__ xl_o, uint32_t* __restrict__ xr_o,
              float* __restrict__ pool_part, int* __restrict__ done_sub,
              int* __restrict__ master,
              const float* __restrict__ obs,
              const float* __restrict__ Wp, const float* __restrict__ bp,
              const float* __restrict__ W1, const float* __restrict__ b1,
              const float* __restrict__ W2, const float* __restrict__ b2,
              const float* __restrict__ W3, const float* __restrict__ b3,
              float* __restrict__ out) {
    __shared__ float smem[MODE == 2 ? HSM : 1024];
    const int tid = threadIdx.x;

    if (MODE == 2 && blockIdx.x >= EGB) {
        // ---------- HEAD block: pre-stage weights, spin, MLP ----------
        const int b = blockIdx.x - EGB;
        float* stage = smem;           // [0, 8192)
        float* sPart = smem + 8192;    // 64
        float* sPool = smem + 8256;    // 16
        float* sIn   = smem + 8272;    // 116
        float* s1a   = smem + 8388;    // 128
        float* s2a   = smem + 8516;    // 128
        float* sWp   = smem + 8644;    // 240
        for (int i = tid; i < 2048; i += 256)
            ((float4*)stage)[i] = ((const float4*)W1)[i];
        if (tid < HC * PO) sWp[tid] = Wp[tid];
        for (int k = tid; k < OBSD; k += 256) sIn[PO + k] = obs[b * OBSD + k];
        if (tid == 0) {
            while (__hip_atomic_load(master, __ATOMIC_RELAXED,
                                     __HIP_MEMORY_SCOPE_AGENT) < NBUCKET) {
                __builtin_amdgcn_s_sleep(16);
            }
        }
        __syncthreads();
        if (tid < 64) {
            int c = tid & 15, q4 = tid >> 4;
            float ps = 0.f;
#pragma unroll
            for (int q = q4; q < NBUCKET; q += 4)
                ps += __hip_atomic_load(&pool_part[q * 256 + b * HC + c],
                                        __ATOMIC_RELAXED, __HIP_MEMORY_SCOPE_AGENT);
            sPart[tid] = ps;
        }
        __syncthreads();
        if (tid < HC)
            sPool[tid] = (sPart[tid] + sPart[16 + tid] + sPart[32 + tid] + sPart[48 + tid]) * (1.0f / NN);
        __syncthreads();
        if (tid < PO) {
            float acc = bp[tid];
#pragma unroll
            for (int c = 0; c < HC; c++) acc = fmaf(sPool[c], sWp[c * PO + tid], acc);
            sIn[tid] = acc;
        }
        __syncthreads();
        float acc1 = (tid < HIDD) ? b1[tid] : 0.f;
        if (tid < HIDD)
            for (int k = 0; k < 64; k++) acc1 = fmaf(sIn[k], stage[k * HIDD + tid], acc1);
        __syncthreads();
        {
            for (int i = tid; i < 1632; i += 256)
                ((float4*)stage)[i] = ((const float4*)(W1 + 64 * HIDD))[i];
            __syncthreads();
            if (tid < HIDD) {
                for (int k = 0; k < 51; k++) acc1 = fmaf(sIn[64 + k], stage[k * HIDD + tid], acc1);
                s1a[tid] = tanhf(acc1);
            }
            __syncthreads();
        }
        float acc2 = (tid < HIDD) ? b2[tid] : 0.f;
#pragma unroll
        for (int ch = 0; ch < 2; ch++) {
            for (int i = tid; i < 2048; i += 256)
                ((float4*)stage)[i] = ((const float4*)(W2 + ch * 64 * HIDD))[i];
            __syncthreads();
            if (tid < HIDD)
                for (int k = 0; k < 64; k++) acc2 = fmaf(s1a[ch * 64 + k], stage[k * HIDD + tid], acc2);
            __syncthreads();
        }
        if (tid < HIDD) s2a[tid] = tanhf(acc2);
        for (int i = tid; i < 960; i += 256)
            ((float4*)stage)[i] = ((const float4*)W3)[i];
        __syncthreads();
        if (tid < NOUT) {
            float acc3 = b3[tid];
            for (int k = 0; k < HIDD; k++) acc3 = fmaf(s2a[k], stage[k * NOUT + tid], acc3);
            out[b * NOUT + tid] = acc3;
        }
        return;
    }

    if (MODE == 1) {
        smem[tid] = Wln[tid];            // sWl [0,256)
        smem[256 + tid] = Wrn[tid];      // sWr [256,512)
        if (tid < HC) { smem[512 + tid] = bln[tid]; smem[528 + tid] = brn[tid]; }
        __syncthreads();
    }
    const int wv   = blockIdx.x * 4 + (tid >> 6);
    const int lane = tid & 63;
    const int h    = lane & 3;
    const float4 a4 = *(const float4*)(attg + h * HD);
    const float4 bias4 = *(const float4*)(biasg + h * HD);
    float psum0 = 0.f, psum1 = 0.f, psum2 = 0.f, psum3 = 0.f;

    for (int n = wv; n < NN; n += NWAVES) {
        float4 xr4;
        {
            uint32_t xrr = xr[(size_t)n * 64 + lane];
            floatx2 q0 = __builtin_amdgcn_cvt_pk_f32_fp8((int)xrr, false);
            floatx2 q1 = __builtin_amdgcn_cvt_pk_f32_fp8((int)xrr, true);
            xr4 = make_float4(q0.x, q0.y, q1.x, q1.y);
        }
        // full-BCAP row: unclamped lane load always in-bounds; slots >= cnt unused
        int vidx = bucket[(size_t)n * BCAP + lane];
        int cnt = __builtin_amdgcn_readfirstlane(cntg[n]);
        cnt = cnt < BCAP ? cnt : BCAP;
        float4 acc = make_float4(0.f, 0.f, 0.f, 0.f);
        float ssum = 0.f;

#define EDGE_CORE(RAW, EXPR)                                                  \
    {                                                                         \
        floatx2 f0 = __builtin_amdgcn_cvt_pk_f32_fp8((int)(RAW), false);      \
        floatx2 f1 = __builtin_amdgcn_cvt_pk_f32_fp8((int)(RAW), true);       \
        float z0 = f0.x + xr4.x; z0 = fmaxf(z0, 0.2f * z0);                   \
        float z1 = f0.y + xr4.y; z1 = fmaxf(z1, 0.2f * z1);                   \
        float z2 = f1.x + xr4.z; z2 = fmaxf(z2, 0.2f * z2);                   \
        float z3 = f1.y + xr4.w; z3 = fmaxf(z3, 0.2f * z3);                   \
        float e = fmaf(z3, a4.w, fmaf(z2, a4.z, fmaf(z1, a4.y, z0 * a4.x)));  \
        float ex = EXPR;                                                      \
        ssum += ex;                                                           \
        acc.x = fmaf(ex, f0.x, acc.x);                                        \
        acc.y = fmaf(ex, f0.y, acc.y);                                        \
        acc.z = fmaf(ex, f1.x, acc.z);                                        \
        acc.w = fmaf(ex, f1.y, acc.w);                                        \
    }
#define EDGE_BODY1(RAW)    EDGE_CORE(RAW, __expf(e))
#define EDGE_BODYM(RAW, M) EDGE_CORE(RAW, (M) * __expf(e))
#define GATHER(S) xl[(size_t)(S) * 64 + lane]

        { const uint32_t r = GATHER(n); EDGE_BODY1(r); }   // self loop
        if (cnt > 0) {
            int i = 0;
            for (; i + 16 <= cnt; i += 16) {
                uint32_t r[16];
#pragma unroll
                for (int u = 0; u < 16; u++) {
                    int s = __builtin_amdgcn_readlane(vidx, i + u);
                    r[u] = GATHER(s);
                }
#pragma unroll
                for (int u = 0; u < 16; u++) EDGE_BODY1(r[u]);
            }
            int rem = cnt - i;
            if (rem > 8) {
                uint32_t r[16];
#pragma unroll
                for (int u = 0; u < 16; u++) {
                    int e2 = i + u;
                    int ec = e2 < cnt ? e2 : cnt - 1;
                    int s = __builtin_amdgcn_readlane(vidx, ec);
                    r[u] = GATHER(s);
                }
#pragma unroll
                for (int u = 0; u < 16; u++) {
                    float m = (i + u < cnt) ? 1.0f : 0.0f;
                    EDGE_BODYM(r[u], m);
                }
            } else if (rem > 0) {
                uint32_t r[8];
#pragma unroll
                for (int u = 0; u < 8; u++) {
                    int e2 = i + u;
                    int ec = e2 < cnt ? e2 : cnt - 1;
                    int s = __builtin_amdgcn_readlane(vidx, ec);
                    r[u] = GATHER(s);
                }
#pragma unroll
                for (int u = 0; u < 8; u++) {
                    float m = (i + u < cnt) ? 1.0f : 0.0f;
                    EDGE_BODYM(r[u], m);
                }
            }
        }
#undef GATHER
#undef EDGE_BODY1
#undef EDGE_BODYM
#undef EDGE_CORE

        float inv = 1.0f / (ssum + 1e-16f);
        float4 o;
        o.x = fmaf(acc.x, inv, bias4.x);
        o.y = fmaf(acc.y, inv, bias4.y);
        o.z = fmaf(acc.z, inv, bias4.z);
        o.w = fmaf(acc.w, inv, bias4.w);

        if (MODE == 1) {
            float accl[4], accr[4];
#pragma unroll
            for (int cj = 0; cj < 4; cj++) {
                accl[cj] = smem[512 + h * 4 + cj];
                accr[cj] = smem[528 + h * 4 + cj];
            }
#pragma unroll
            for (int m = 0; m < 4; m++) {
                float4 vals = (m == 0) ? o : shfl_xor4(o, m);
                int fbase = ((h ^ m) << 2);
                float vv[4] = {vals.x, vals.y, vals.z, vals.w};
#pragma unroll
                for (int j = 0; j < 4; j++) {
                    const float4 wl = *(const float4*)&smem[(fbase + j) * HC + (h << 2)];
                    const float4 wr = *(const float4*)&smem[256 + (fbase + j) * HC + (h << 2)];
                    float v = vv[j];
                    accl[0] = fmaf(v, wl.x, accl[0]);
                    accl[1] = fmaf(v, wl.y, accl[1]);
                    accl[2] = fmaf(v, wl.z, accl[2]);
                    accl[3] = fmaf(v, wl.w, accl[3]);
                    accr[0] = fmaf(v, wr.x, accr[0]);
                    accr[1] = fmaf(v, wr.y, accr[1]);
                    accr[2] = fmaf(v, wr.z, accr[2]);
                    accr[3] = fmaf(v, wr.w, accr[3]);
                }
            }
            xl_o[(size_t)n * 64 + lane] = pack_fp8x4(accl[0], accl[1], accl[2], accl[3]);
            xr_o[(size_t)n * 64 + lane] = pack_fp8x4(accr[0], accr[1], accr[2], accr[3]);
        } else {
            psum0 += o.x; psum1 += o.y; psum2 += o.z; psum3 += o.w;
        }
    }

    if (MODE == 2) {
        // block-reduce psums -> 64-bucket atomic pool + relaxed ticket
        *(float4*)&smem[tid * 4] = make_float4(psum0, psum1, psum2, psum3);
        __syncthreads();
        if (tid < 64) {
            float4 s0 = *(const float4*)&smem[tid * 4];
            float4 s1v = *(const float4*)&smem[(64 + tid) * 4];
            float4 s2v = *(const float4*)&smem[(128 + tid) * 4];
            float4 s3v = *(const float4*)&smem[(192 + tid) * 4];
            float* dp = pool_part + (blockIdx.x & (NBUCKET - 1)) * 256 + tid * 4;
            atomicAdd(dp + 0, s0.x + s1v.x + s2v.x + s3v.x);
            atomicAdd(dp + 1, s0.y + s1v.y + s2v.y + s3v.y);
            atomicAdd(dp + 2, s0.z + s1v.z + s2v.z + s3v.z);
            atomicAdd(dp + 3, s0.w + s1v.w + s2v.w + s3v.w);
        }
        if (tid == 0) {
            asm volatile("s_waitcnt vmcnt(0)" ::: "memory");
            int s = blockIdx.x & 63;
            const int quota = EGB / 64;   // 10, exact (640 % 64 == 0)
            int old = __hip_atomic_fetch_add(&done_sub[s], 1, __ATOMIC_RELAXED,
                                             __HIP_MEMORY_SCOPE_AGENT);
            if (old == quota - 1)
                __hip_atomic_fetch_add(master, 1, __ATOMIC_RELAXED,
                                       __HIP_MEMORY_SCOPE_AGENT);
        }
    }
}

extern "C" void kernel_launch(void* const* d_in, const int* in_sizes, int n_in,
                              void* d_out, int out_size, void* d_ws, size_t ws_size,
                              hipStream_t stream) {
    const float* x    = (const float*)d_in[0];
    const float* obs  = (const float*)d_in[1];
    const int*   src  = (const int*)d_in[2];
    const int*   dst  = (const int*)d_in[3];
    const float* W0l  = (const float*)d_in[4];
    const float* W0r  = (const float*)d_in[5];
    const float* b0l  = (const float*)d_in[6];
    const float* b0r  = (const float*)d_in[7];
    const float* Wl   = (const float*)d_in[8];
    const float* Wr   = (const float*)d_in[9];
    const float* bl   = (const float*)d_in[10];
    const float* br   = (const float*)d_in[11];
    const float* att  = (const float*)d_in[12];
    const float* bias = (const float*)d_in[13];
    const float* Wp   = (const float*)d_in[14];
    const float* bp   = (const float*)d_in[15];
    const float* W1   = (const float*)d_in[16];
    const float* b1   = (const float*)d_in[17];
    const float* W2   = (const float*)d_in[18];
    const float* b2   = (const float*)d_in[19];
    const float* W3   = (const float*)d_in[20];
    const float* b3   = (const float*)d_in[21];
    float* out = (float*)d_out;

    size_t off = 0;
    auto take = [&](size_t bytes) -> void* {
        void* ptr = (char*)d_ws + off;
        off += (bytes + 255) & ~(size_t)255;
        return ptr;
    };
    int*      cnt       = (int*)take(NN * sizeof(int));
    float*    pool_part = (float*)take(NBUCKET * 256 * sizeof(float));
    int*      done_sub  = (int*)take(64 * sizeof(int));
    int*      master    = (int*)take(64 * sizeof(int));
    int*      bucket    = (int*)take((size_t)NN * BCAP * sizeof(int));
    uint32_t* xlA       = (uint32_t*)take((size_t)NN * 64 * sizeof(uint32_t));
    uint32_t* xrA       = (uint32_t*)take((size_t)NN * 64 * sizeof(uint32_t));
    uint32_t* xlB       = (uint32_t*)take((size_t)NN * 64 * sizeof(uint32_t));
    uint32_t* xrB       = (uint32_t*)take((size_t)NN * 64 * sizeof(uint32_t));

    // zero cnt + pool_part + done_sub + master in one memset (contiguous)
    size_t zspan = (size_t)((char*)(master + 64) - (char*)cnt);
    hipMemsetAsync(cnt, 0, zspan, stream);

    k_build_xform0<<<625 + 40 * NB, 256, 0, stream>>>(src, dst, cnt, bucket,
                                                      x, W0l, W0r, b0l, b0r, xlA, xrA);

    // layers 0..2: edge + fused next-layer transform (ping-pong buffers)
    k_edge_f<1><<<EGB, 256, 0, stream>>>(xlA, xrA, cnt, bucket,
                                         att + 0 * 16, bias + 0 * 16,
                                         Wl + 0 * 256, Wr + 0 * 256, bl + 0 * 16, br + 0 * 16,
                                         xlB, xrB, nullptr, nullptr, nullptr,
                                         nullptr, nullptr, nullptr, nullptr, nullptr,
                                         nullptr, nullptr, nullptr, nullptr, nullptr);
    k_edge_f<1><<<EGB, 256, 0, stream>>>(xlB, xrB, cnt, bucket,
                                         att + 1 * 16, bias + 1 * 16,
                                         Wl + 1 * 256, Wr + 1 * 256, bl + 1 * 16, br + 1 * 16,
                                         xlA, xrA, nullptr, nullptr, nullptr,
                                         nullptr, nullptr, nullptr, nullptr, nullptr,
                                         nullptr, nullptr, nullptr, nullptr, nullptr);
    k_edge_f<1><<<EGB, 256, 0, stream>>>(xlA, xrA, cnt, bucket,
                                         att + 2 * 16, bias + 2 * 16,
                                         Wl + 2 * 256, Wr + 2 * 256, bl + 2 * 16, br + 2 * 16,
                                         xlB, xrB, nullptr, nullptr, nullptr,
                                         nullptr, nullptr, nullptr, nullptr, nullptr,
                                         nullptr, nullptr, nullptr, nullptr, nullptr);
    // layer 3: edge + pool + fused head (16 extra blocks, pre-staged weights)
    k_edge_f<2><<<EGB + NB, 256, 0, stream>>>(xlB, xrB, cnt, bucket,
                                              att + 3 * 16, bias + 3 * 16,
                                              nullptr, nullptr, nullptr, nullptr,
                                              nullptr, nullptr, pool_part, done_sub,
                                              master, obs, Wp, bp, W1, b1, W2, b2,
                                              W3, b3, out);
}

// Round 19
// 125.442 us; speedup vs baseline: 1.8603x; 1.8603x over previous
//
#include <hip/hip_runtime.h>
#include <cstdint>
#include <cstddef>

#define NN   10000
#define NE   160000
#define NB   16
#define FIN  32
#define HC   16
#define NH   4
#define HD   4
#define OBSD 100
#define NOUT 30
#define HIDD 128
#define PO   15
#define BCAP 64
#define NBUCKET 64
#define EG   2500          // edge blocks: NN*64/256 exactly (1 node per wave)
#define HSM  8884          // MODE2 smem floats

typedef float floatx2 __attribute__((ext_vector_type(2)));

__device__ inline uint32_t pack_fp8x4(float a, float b, float c, float d) {
    int p = __builtin_amdgcn_cvt_pk_fp8_f32(a, b, 0, false);
    p = __builtin_amdgcn_cvt_pk_fp8_f32(c, d, p, true);
    return (uint32_t)p;
}

__device__ inline float4 shfl_xor4(float4 v, int m) {
    float4 r;
    r.x = __shfl_xor(v.x, m, 64);
    r.y = __shfl_xor(v.y, m, 64);
    r.z = __shfl_xor(v.z, m, 64);
    r.w = __shfl_xor(v.w, m, 64);
    return r;
}

// ---------------- bucket-CSR build + layer-0 transform (fat kernel) --------
__global__ void k_build_xform0(const int* __restrict__ src, const int* __restrict__ dst,
                               int* __restrict__ cnt, int* __restrict__ bucket,
                               const float* __restrict__ x,
                               const float* __restrict__ Wlg, const float* __restrict__ Wrg,
                               const float* __restrict__ blg, const float* __restrict__ brg,
                               uint32_t* __restrict__ xl, uint32_t* __restrict__ xr) {
    int bid = blockIdx.x;
    if (bid < 625) {
        int e = bid * 256 + threadIdx.x;
        if (e < NE) {
            int d = dst[e];
            int p = atomicAdd(&cnt[d], 1);
            if (p < BCAP) bucket[(size_t)d * BCAP + p] = src[e];
        }
        return;
    }
    __shared__ float sWl[FIN * HC], sWr[FIN * HC], sbl[HC], sbr[HC];
    for (int i = threadIdx.x; i < FIN * HC; i += 256) { sWl[i] = Wlg[i]; sWr[i] = Wrg[i]; }
    if (threadIdx.x < HC) { sbl[threadIdx.x] = blg[threadIdx.x]; sbr[threadIdx.x] = brg[threadIdx.x]; }
    __syncthreads();
    int local = bid - 625;
    int b = local / 40;
    int n = (local % 40) * 256 + threadIdx.x;
    if (n >= NN) return;
    const float4* xp4 = (const float4*)(x + ((size_t)b * NN + n) * FIN);
    float4 rowv[8];
#pragma unroll
    for (int f4 = 0; f4 < 8; f4++) rowv[f4] = xp4[f4];
    const float* row = (const float*)rowv;
    float al[HC], ar[HC];
#pragma unroll
    for (int c = 0; c < HC; c++) { al[c] = sbl[c]; ar[c] = sbr[c]; }
#pragma unroll
    for (int f = 0; f < FIN; f++) {
        float v = row[f];
#pragma unroll
        for (int c = 0; c < HC; c++) {
            al[c] = fmaf(v, sWl[f * HC + c], al[c]);
            ar[c] = fmaf(v, sWr[f * HC + c], ar[c]);
        }
    }
    uint32_t* xlo = xl + ((size_t)n * NB + b) * 4;
    uint32_t* xro = xr + ((size_t)n * NB + b) * 4;
#pragma unroll
    for (int hh = 0; hh < 4; hh++) {
        xlo[hh] = pack_fp8x4(al[hh * 4 + 0], al[hh * 4 + 1], al[hh * 4 + 2], al[hh * 4 + 3]);
        xro[hh] = pack_fp8x4(ar[hh * 4 + 0], ar[hh * 4 + 1], ar[hh * 4 + 2], ar[hh * 4 + 3]);
    }
}

// ---------------- fused edge softmax + aggregate ----------------
// one wave per node (contiguous node<->wave map: critical for L2/write locality);
// lane = b*4 + h; one uint = 4 fp8 = one head's dims.
// MODE 1: fused next-layer 16x16 l/r transforms -> xl'(fp8)/xr'(fp8).
// MODE 2: pool via 64-bucket atomics + relaxed done-tickets; 16 extra HEAD
//         blocks (bid>=EG) pre-stage weights, spin, then compute the MLP.
template <int MODE>
__global__ __launch_bounds__(256, 4)
void k_edge_f(const uint32_t* __restrict__ xl, const uint32_t* __restrict__ xr,
              const int* __restrict__ cntg, const int* __restrict__ bucket,
              const float* __restrict__ attg, const float* __restrict__ biasg,
              const float* __restrict__ Wln, const float* __restrict__ Wrn,
              const float* __restrict__ bln, const float* __restrict__ brn,
              uint32_t* __restrict__ xl_o, uint32_t* __restrict__ xr_o,
              float* __restrict__ pool_part, int* __restrict__ done_sub,
              int* __restrict__ master,
              const float* __restrict__ obs,
              const float* __restrict__ Wp, const float* __restrict__ bp,
              const float* __restrict__ W1, const float* __restrict__ b1,
              const float* __restrict__ W2, const float* __restrict__ b2,
              const float* __restrict__ W3, const float* __restrict__ b3,
              float* __restrict__ out) {
    __shared__ float smem[MODE == 2 ? HSM : 1024];
    const int tid = threadIdx.x;

    if (MODE == 2 && blockIdx.x >= EG) {
        // ---------- HEAD block: pre-stage weights, spin, MLP ----------
        const int b = blockIdx.x - EG;
        float* stage = smem;           // [0, 8192)
        float* sPart = smem + 8192;    // 64
        float* sPool = smem + 8256;    // 16
        float* sIn   = smem + 8272;    // 116
        float* s1a   = smem + 8388;    // 128
        float* s2a   = smem + 8516;    // 128
        float* sWp   = smem + 8644;    // 240
        for (int i = tid; i < 2048; i += 256)
            ((float4*)stage)[i] = ((const float4*)W1)[i];
        if (tid < HC * PO) sWp[tid] = Wp[tid];
        for (int k = tid; k < OBSD; k += 256) sIn[PO + k] = obs[b * OBSD + k];
        if (tid == 0) {
            while (__hip_atomic_load(master, __ATOMIC_RELAXED,
                                     __HIP_MEMORY_SCOPE_AGENT) < NBUCKET) {
                __builtin_amdgcn_s_sleep(16);
            }
        }
        __syncthreads();
        if (tid < 64) {
            int c = tid & 15, q4 = tid >> 4;
            float ps = 0.f;
#pragma unroll
            for (int q = q4; q < NBUCKET; q += 4)
                ps += __hip_atomic_load(&pool_part[q * 256 + b * HC + c],
                                        __ATOMIC_RELAXED, __HIP_MEMORY_SCOPE_AGENT);
            sPart[tid] = ps;
        }
        __syncthreads();
        if (tid < HC)
            sPool[tid] = (sPart[tid] + sPart[16 + tid] + sPart[32 + tid] + sPart[48 + tid]) * (1.0f / NN);
        __syncthreads();
        if (tid < PO) {
            float acc = bp[tid];
#pragma unroll
            for (int c = 0; c < HC; c++) acc = fmaf(sPool[c], sWp[c * PO + tid], acc);
            sIn[tid] = acc;
        }
        __syncthreads();
        float acc1 = (tid < HIDD) ? b1[tid] : 0.f;
        if (tid < HIDD)
            for (int k = 0; k < 64; k++) acc1 = fmaf(sIn[k], stage[k * HIDD + tid], acc1);
        __syncthreads();
        {
            for (int i = tid; i < 1632; i += 256)
                ((float4*)stage)[i] = ((const float4*)(W1 + 64 * HIDD))[i];
            __syncthreads();
            if (tid < HIDD) {
                for (int k = 0; k < 51; k++) acc1 = fmaf(sIn[64 + k], stage[k * HIDD + tid], acc1);
                s1a[tid] = tanhf(acc1);
            }
            __syncthreads();
        }
        float acc2 = (tid < HIDD) ? b2[tid] : 0.f;
#pragma unroll
        for (int ch = 0; ch < 2; ch++) {
            for (int i = tid; i < 2048; i += 256)
                ((float4*)stage)[i] = ((const float4*)(W2 + ch * 64 * HIDD))[i];
            __syncthreads();
            if (tid < HIDD)
                for (int k = 0; k < 64; k++) acc2 = fmaf(s1a[ch * 64 + k], stage[k * HIDD + tid], acc2);
            __syncthreads();
        }
        if (tid < HIDD) s2a[tid] = tanhf(acc2);
        for (int i = tid; i < 960; i += 256)
            ((float4*)stage)[i] = ((const float4*)W3)[i];
        __syncthreads();
        if (tid < NOUT) {
            float acc3 = b3[tid];
            for (int k = 0; k < HIDD; k++) acc3 = fmaf(s2a[k], stage[k * NOUT + tid], acc3);
            out[b * NOUT + tid] = acc3;
        }
        return;
    }

    if (MODE == 1) {
        smem[tid] = Wln[tid];            // sWl [0,256)
        smem[256 + tid] = Wrn[tid];      // sWr [256,512)
        if (tid < HC) { smem[512 + tid] = bln[tid]; smem[528 + tid] = brn[tid]; }
        __syncthreads();
    }
    const int wave = (blockIdx.x * 256 + tid) >> 6;
    const int lane = tid & 63;
    const int n = wave;
    const int h = lane & 3;
    const float4 a4 = *(const float4*)(attg + h * HD);
    const float4 bias4 = *(const float4*)(biasg + h * HD);
    float4 xr4;
    {
        uint32_t xrr = xr[(size_t)n * 64 + lane];
        floatx2 q0 = __builtin_amdgcn_cvt_pk_f32_fp8((int)xrr, false);
        floatx2 q1 = __builtin_amdgcn_cvt_pk_f32_fp8((int)xrr, true);
        xr4 = make_float4(q0.x, q0.y, q1.x, q1.y);
    }
    // full-BCAP row: unclamped lane load always in-bounds; slots >= cnt unused
    int vidx = bucket[(size_t)n * BCAP + lane];
    int cnt = __builtin_amdgcn_readfirstlane(cntg[n]);
    cnt = cnt < BCAP ? cnt : BCAP;
    float4 acc = make_float4(0.f, 0.f, 0.f, 0.f);
    float ssum = 0.f;

#define EDGE_CORE(RAW, EXPR)                                                  \
    {                                                                         \
        floatx2 f0 = __builtin_amdgcn_cvt_pk_f32_fp8((int)(RAW), false);      \
        floatx2 f1 = __builtin_amdgcn_cvt_pk_f32_fp8((int)(RAW), true);       \
        float z0 = f0.x + xr4.x; z0 = fmaxf(z0, 0.2f * z0);                   \
        float z1 = f0.y + xr4.y; z1 = fmaxf(z1, 0.2f * z1);                   \
        float z2 = f1.x + xr4.z; z2 = fmaxf(z2, 0.2f * z2);                   \
        float z3 = f1.y + xr4.w; z3 = fmaxf(z3, 0.2f * z3);                   \
        float e = fmaf(z3, a4.w, fmaf(z2, a4.z, fmaf(z1, a4.y, z0 * a4.x)));  \
        float ex = EXPR;                                                      \
        ssum += ex;                                                           \
        acc.x = fmaf(ex, f0.x, acc.x);                                        \
        acc.y = fmaf(ex, f0.y, acc.y);                                        \
        acc.z = fmaf(ex, f1.x, acc.z);                                        \
        acc.w = fmaf(ex, f1.y, acc.w);                                        \
    }
#define EDGE_BODY1(RAW)    EDGE_CORE(RAW, __expf(e))
#define EDGE_BODYM(RAW, M) EDGE_CORE(RAW, (M) * __expf(e))
#define GATHER(S) xl[(size_t)(S) * 64 + lane]

    { const uint32_t r = GATHER(n); EDGE_BODY1(r); }   // self loop
    if (cnt > 0) {
        int i = 0;
        for (; i + 16 <= cnt; i += 16) {           // full batches: no mask
            uint32_t r[16];
#pragma unroll
            for (int u = 0; u < 16; u++) {
                int s = __builtin_amdgcn_readlane(vidx, i + u);
                r[u] = GATHER(s);
            }
#pragma unroll
            for (int u = 0; u < 16; u++) EDGE_BODY1(r[u]);
        }
        int rem = cnt - i;
        if (rem > 8) {                             // masked 16-tail
            uint32_t r[16];
#pragma unroll
            for (int u = 0; u < 16; u++) {
                int e2 = i + u;
                int ec = e2 < cnt ? e2 : cnt - 1;
                int s = __builtin_amdgcn_readlane(vidx, ec);
                r[u] = GATHER(s);
            }
#pragma unroll
            for (int u = 0; u < 16; u++) {
                float m = (i + u < cnt) ? 1.0f : 0.0f;
                EDGE_BODYM(r[u], m);
            }
        } else if (rem > 0) {                      // masked 8-tail
            uint32_t r[8];
#pragma unroll
            for (int u = 0; u < 8; u++) {
                int e2 = i + u;
                int ec = e2 < cnt ? e2 : cnt - 1;
                int s = __builtin_amdgcn_readlane(vidx, ec);
                r[u] = GATHER(s);
            }
#pragma unroll
            for (int u = 0; u < 8; u++) {
                float m = (i + u < cnt) ? 1.0f : 0.0f;
                EDGE_BODYM(r[u], m);
            }
        }
    }
#undef GATHER
#undef EDGE_BODY1
#undef EDGE_BODYM
#undef EDGE_CORE

    float inv = 1.0f / (ssum + 1e-16f);
    float4 o;
    o.x = fmaf(acc.x, inv, bias4.x);
    o.y = fmaf(acc.y, inv, bias4.y);
    o.z = fmaf(acc.z, inv, bias4.z);
    o.w = fmaf(acc.w, inv, bias4.w);

    if (MODE == 1) {
        float accl[4], accr[4];
#pragma unroll
        for (int cj = 0; cj < 4; cj++) {
            accl[cj] = smem[512 + h * 4 + cj];
            accr[cj] = smem[528 + h * 4 + cj];
        }
#pragma unroll
        for (int m = 0; m < 4; m++) {
            float4 vals = (m == 0) ? o : shfl_xor4(o, m);
            int fbase = ((h ^ m) << 2);
            float vv[4] = {vals.x, vals.y, vals.z, vals.w};
#pragma unroll
            for (int j = 0; j < 4; j++) {
                const float4 wl = *(const float4*)&smem[(fbase + j) * HC + (h << 2)];
                const float4 wr = *(const float4*)&smem[256 + (fbase + j) * HC + (h << 2)];
                float v = vv[j];
                accl[0] = fmaf(v, wl.x, accl[0]);
                accl[1] = fmaf(v, wl.y, accl[1]);
                accl[2] = fmaf(v, wl.z, accl[2]);
                accl[3] = fmaf(v, wl.w, accl[3]);
                accr[0] = fmaf(v, wr.x, accr[0]);
                accr[1] = fmaf(v, wr.y, accr[1]);
                accr[2] = fmaf(v, wr.z, accr[2]);
                accr[3] = fmaf(v, wr.w, accr[3]);
            }
        }
        xl_o[(size_t)n * 64 + lane] = pack_fp8x4(accl[0], accl[1], accl[2], accl[3]);
        xr_o[(size_t)n * 64 + lane] = pack_fp8x4(accr[0], accr[1], accr[2], accr[3]);
    } else {
        // MODE 2: block-reduce 4 nodes -> 64-bucket atomic pool + relaxed ticket
        *(float4*)&smem[tid * 4] = o;
        __syncthreads();
        if (tid < 64) {
            float4 s0 = *(const float4*)&smem[tid * 4];
            float4 s1v = *(const float4*)&smem[(64 + tid) * 4];
            float4 s2v = *(const float4*)&smem[(128 + tid) * 4];
            float4 s3v = *(const float4*)&smem[(192 + tid) * 4];
            float* dp = pool_part + (blockIdx.x & (NBUCKET - 1)) * 256 + tid * 4;
            atomicAdd(dp + 0, s0.x + s1v.x + s2v.x + s3v.x);
            atomicAdd(dp + 1, s0.y + s1v.y + s2v.y + s3v.y);
            atomicAdd(dp + 2, s0.z + s1v.z + s2v.z + s3v.z);
            atomicAdd(dp + 3, s0.w + s1v.w + s2v.w + s3v.w);
        }
        if (tid == 0) {
            asm volatile("s_waitcnt vmcnt(0)" ::: "memory");
            int s = blockIdx.x & 63;
            int quota = (s < (EG & 63)) ? (EG / 64 + 1) : (EG / 64);  // 40 or 39
            int old = __hip_atomic_fetch_add(&done_sub[s], 1, __ATOMIC_RELAXED,
                                             __HIP_MEMORY_SCOPE_AGENT);
            if (old == quota - 1)
                __hip_atomic_fetch_add(master, 1, __ATOMIC_RELAXED,
                                       __HIP_MEMORY_SCOPE_AGENT);
        }
    }
}

extern "C" void kernel_launch(void* const* d_in, const int* in_sizes, int n_in,
                              void* d_out, int out_size, void* d_ws, size_t ws_size,
                              hipStream_t stream) {
    const float* x    = (const float*)d_in[0];
    const float* obs  = (const float*)d_in[1];
    const int*   src  = (const int*)d_in[2];
    const int*   dst  = (const int*)d_in[3];
    const float* W0l  = (const float*)d_in[4];
    const float* W0r  = (const float*)d_in[5];
    const float* b0l  = (const float*)d_in[6];
    const float* b0r  = (const float*)d_in[7];
    const float* Wl   = (const float*)d_in[8];
    const float* Wr   = (const float*)d_in[9];
    const float* bl   = (const float*)d_in[10];
    const float* br   = (const float*)d_in[11];
    const float* att  = (const float*)d_in[12];
    const float* bias = (const float*)d_in[13];
    const float* Wp   = (const float*)d_in[14];
    const float* bp   = (const float*)d_in[15];
    const float* W1   = (const float*)d_in[16];
    const float* b1   = (const float*)d_in[17];
    const float* W2   = (const float*)d_in[18];
    const float* b2   = (const float*)d_in[19];
    const float* W3   = (const float*)d_in[20];
    const float* b3   = (const float*)d_in[21];
    float* out = (float*)d_out;

    size_t off = 0;
    auto take = [&](size_t bytes) -> void* {
        void* ptr = (char*)d_ws + off;
        off += (bytes + 255) & ~(size_t)255;
        return ptr;
    };
    int*      cnt       = (int*)take(NN * sizeof(int));
    float*    pool_part = (float*)take(NBUCKET * 256 * sizeof(float));
    int*      done_sub  = (int*)take(64 * sizeof(int));
    int*      master    = (int*)take(64 * sizeof(int));
    int*      bucket    = (int*)take((size_t)NN * BCAP * sizeof(int));
    uint32_t* xlA       = (uint32_t*)take((size_t)NN * 64 * sizeof(uint32_t));
    uint32_t* xrA       = (uint32_t*)take((size_t)NN * 64 * sizeof(uint32_t));
    uint32_t* xlB       = (uint32_t*)take((size_t)NN * 64 * sizeof(uint32_t));
    uint32_t* xrB       = (uint32_t*)take((size_t)NN * 64 * sizeof(uint32_t));

    // zero cnt + pool_part + done_sub + master in one memset (contiguous)
    size_t zspan = (size_t)((char*)(master + 64) - (char*)cnt);
    hipMemsetAsync(cnt, 0, zspan, stream);

    k_build_xform0<<<625 + 40 * NB, 256, 0, stream>>>(src, dst, cnt, bucket,
                                                      x, W0l, W0r, b0l, b0r, xlA, xrA);

    // layers 0..2: edge + fused next-layer transform (ping-pong buffers)
    k_edge_f<1><<<EG, 256, 0, stream>>>(xlA, xrA, cnt, bucket,
                                        att + 0 * 16, bias + 0 * 16,
                                        Wl + 0 * 256, Wr + 0 * 256, bl + 0 * 16, br + 0 * 16,
                                        xlB, xrB, nullptr, nullptr, nullptr,
                                        nullptr, nullptr, nullptr, nullptr, nullptr,
                                        nullptr, nullptr, nullptr, nullptr, nullptr);
    k_edge_f<1><<<EG, 256, 0, stream>>>(xlB, xrB, cnt, bucket,
                                        att + 1 * 16, bias + 1 * 16,
                                        Wl + 1 * 256, Wr + 1 * 256, bl + 1 * 16, br + 1 * 16,
                                        xlA, xrA, nullptr, nullptr, nullptr,
                                        nullptr, nullptr, nullptr, nullptr, nullptr,
                                        nullptr, nullptr, nullptr, nullptr, nullptr);
    k_edge_f<1><<<EG, 256, 0, stream>>>(xlA, xrA, cnt, bucket,
                                        att + 2 * 16, bias + 2 * 16,
                                        Wl + 2 * 256, Wr + 2 * 256, bl + 2 * 16, br + 2 * 16,
                                        xlB, xrB, nullptr, nullptr, nullptr,
                                        nullptr, nullptr, nullptr, nullptr, nullptr,
                                        nullptr, nullptr, nullptr, nullptr, nullptr);
    // layer 3: edge + pool + fused head (16 extra blocks, pre-staged weights)
    k_edge_f<2><<<EG + NB, 256, 0, stream>>>(xlB, xrB, cnt, bucket,
                                             att + 3 * 16, bias + 3 * 16,
                                             nullptr, nullptr, nullptr, nullptr,
                                             nullptr, nullptr, pool_part, done_sub,
                                             master, obs, Wp, bp, W1, b1, W2, b2,
                                             W3, b3, out);
}